// Round 13
// baseline (221.348 us; speedup 1.0000x reference)
//
#include <hip/hip_runtime.h>
#include <hip/hip_bf16.h>

#define HID 128
#define NH  4          // heads
#define FEAT (NH*HID)  // 512 per node per projection
#define F2   (2*FEAT)  // xl|xr packed row stride = 1024
#define NEG_SLOPE 0.2f
#define BN_EPS 1e-5f
#define CAP  128       // max buffered edges per node (deg ~ Poisson(32); fallback if exceeded)

typedef __attribute__((ext_vector_type(8))) short bf16x8;   // 8 bf16 = 4 VGPR
typedef __attribute__((ext_vector_type(4))) float f32x4;
typedef __attribute__((ext_vector_type(2))) float f32x2;

// ---------- helpers ----------
__device__ inline ushort f2bf(float f) {     // RNE f32 -> bf16
    unsigned u = __float_as_uint(f);
    return (ushort)((u + 0x7fffu + ((u >> 16) & 1u)) >> 16);
}
// unpack 8 bf16 into 4 float2 (channel pairs)
__device__ inline void ubf8p(const ushort* p, f32x2* o) {
    uint4 q = *(const uint4*)p;
    o[0] = f32x2{__uint_as_float(q.x << 16), __uint_as_float(q.x & 0xffff0000u)};
    o[1] = f32x2{__uint_as_float(q.y << 16), __uint_as_float(q.y & 0xffff0000u)};
    o[2] = f32x2{__uint_as_float(q.z << 16), __uint_as_float(q.z & 0xffff0000u)};
    o[3] = f32x2{__uint_as_float(q.w << 16), __uint_as_float(q.w & 0xffff0000u)};
}

// ---------- transpose + cast four K_z x Nc f32 mats -> [Nc][K_z] bf16 ----------
__global__ __launch_bounds__(256) void transpose_cast4(const float* __restrict__ in0,
                                                       const float* __restrict__ in1,
                                                       const float* __restrict__ in2,
                                                       const float* __restrict__ in3,
                                                       ushort* __restrict__ out0,
                                                       ushort* __restrict__ out1,
                                                       ushort* __restrict__ out2,
                                                       ushort* __restrict__ out3,
                                                       int K01, int K23, int Nc)
{
    const int z = blockIdx.z;
    const float* in  = (z == 0) ? in0 : (z == 1) ? in1 : (z == 2) ? in2 : in3;
    ushort*      out = (z == 0) ? out0 : (z == 1) ? out1 : (z == 2) ? out2 : out3;
    const int K = (z < 2) ? K01 : K23;
    int bk = blockIdx.x * 32, bc = blockIdx.y * 32;
    if (bk >= K) return;
    __shared__ float t[32][33];
    int r = threadIdx.x >> 3, c4 = (threadIdx.x & 7) * 4;
    float4 v = *(const float4*)(in + (size_t)(bk + r) * Nc + bc + c4);
    t[r][c4 + 0] = v.x; t[r][c4 + 1] = v.y; t[r][c4 + 2] = v.z; t[r][c4 + 3] = v.w;
    __syncthreads();
    ushort4 o;
    o.x = f2bf(t[c4 + 0][r]); o.y = f2bf(t[c4 + 1][r]);
    o.z = f2bf(t[c4 + 2][r]); o.w = f2bf(t[c4 + 3][r]);
    *(ushort4*)(out + (size_t)(bc + r) * K + bk + c4) = o;
}

// ---------- bf16 MFMA GEMM: C[M][Nc] = A[M][K] @ Bt[Nc][K]^T ----------
// 128x128 tile, BK=32, 256 threads = 4 waves (2x2), per wave 4x4 frags 16x16.
// CVT=true: A is f32, converted to bf16 during LDS staging (fuses the cast).
template <bool CVT>
__global__ __launch_bounds__(256) void gemm_bf16(const void* __restrict__ Av,
                                                 const ushort* __restrict__ Bt,
                                                 ushort* __restrict__ C,
                                                 int M, int Nc, int K)
{
    __shared__ __align__(16) ushort As[128 * 40];  // row stride 40 (pad 8)
    __shared__ __align__(16) ushort Bs[128 * 40];
    const int bm = blockIdx.x * 128;
    const int bn = blockIdx.y * 128;
    const int tid = threadIdx.x;
    const int wid = tid >> 6, lane = tid & 63;
    const int wr = wid >> 1, wc = wid & 1;
    const int l15 = lane & 15, l4 = lane >> 4;

    f32x4 acc[4][4] = {};

    for (int k0 = 0; k0 < K; k0 += 32) {
        #pragma unroll
        for (int s = 0; s < 2; ++s) {               // A,B: 512 chunks of 8 elems each
            int c = tid + s * 256;
            int r = c >> 2, cc = (c & 3) * 8;
            int gr = bm + r;
            if (CVT) {
                const float* A = (const float*)Av;
                float4 lo = make_float4(0.f, 0.f, 0.f, 0.f);
                float4 hi = make_float4(0.f, 0.f, 0.f, 0.f);
                if (gr < M) {
                    lo = *(const float4*)(A + (size_t)gr * K + k0 + cc);
                    hi = *(const float4*)(A + (size_t)gr * K + k0 + cc + 4);
                }
                ushort4 p0 = make_ushort4(f2bf(lo.x), f2bf(lo.y), f2bf(lo.z), f2bf(lo.w));
                ushort4 p1 = make_ushort4(f2bf(hi.x), f2bf(hi.y), f2bf(hi.z), f2bf(hi.w));
                *(ushort4*)&As[r * 40 + cc] = p0;
                *(ushort4*)&As[r * 40 + cc + 4] = p1;
            } else {
                const ushort* A = (const ushort*)Av;
                uint4 v = make_uint4(0, 0, 0, 0);
                if (gr < M) v = *(const uint4*)(A + (size_t)gr * K + k0 + cc);
                *(uint4*)&As[r * 40 + cc] = v;
            }
            uint4 w = *(const uint4*)(Bt + (size_t)(bn + r) * K + k0 + cc);
            *(uint4*)&Bs[r * 40 + cc] = w;
        }
        __syncthreads();
        bf16x8 bfr[4];
        #pragma unroll
        for (int n = 0; n < 4; ++n)
            bfr[n] = *(const bf16x8*)&Bs[(wc * 64 + n * 16 + l15) * 40 + l4 * 8];
        #pragma unroll
        for (int m = 0; m < 4; ++m) {
            bf16x8 afr = *(const bf16x8*)&As[(wr * 64 + m * 16 + l15) * 40 + l4 * 8];
            #pragma unroll
            for (int n = 0; n < 4; ++n)
                acc[m][n] = __builtin_amdgcn_mfma_f32_16x16x32_bf16(afr, bfr[n], acc[m][n], 0, 0, 0);
        }
        __syncthreads();
    }
    #pragma unroll
    for (int m = 0; m < 4; ++m)
        #pragma unroll
        for (int n = 0; n < 4; ++n)
            #pragma unroll
            for (int r = 0; r < 4; ++r) {
                int row = bm + wr * 64 + m * 16 + l4 * 4 + r;
                int col = bn + wc * 64 + n * 16 + l15;
                if (row < M) C[(size_t)row * Nc + col] = f2bf(acc[m][n][r]);
            }
}

// ---------- CSR build ----------
__global__ __launch_bounds__(256) void csr_count(const int* __restrict__ ei,
                                                 int* __restrict__ deg,
                                                 int E, int Etot)
{
    int i = blockIdx.x * 256 + threadIdx.x;
    if (i >= Etot) return;
    int dst = (i < E) ? ei[E + i] : (i - E);
    atomicAdd(&deg[dst], 1);
}

__global__ __launch_bounds__(1024) void scan_rowptr(const int* __restrict__ deg,
                                                    int* __restrict__ rowptr,
                                                    int* __restrict__ cursor,
                                                    int N)
{
    __shared__ int part[1024];
    int t = threadIdx.x;
    int chunk = (N + 1023) / 1024;
    int lo = t * chunk;
    int hi = lo + chunk; if (hi > N) hi = N; if (lo > N) lo = N;
    int s = 0;
    for (int i = lo; i < hi; ++i) s += deg[i];
    part[t] = s;
    __syncthreads();
    for (int off = 1; off < 1024; off <<= 1) {
        int v = (t >= off) ? part[t - off] : 0;
        __syncthreads();
        part[t] += v;
        __syncthreads();
    }
    int base = (t == 0) ? 0 : part[t - 1];
    for (int i = lo; i < hi; ++i) {
        rowptr[i] = base;
        cursor[i] = base;
        base += deg[i];
    }
    if (t == 1023) rowptr[N] = part[1023];
}

__global__ __launch_bounds__(256) void csr_fill(const int* __restrict__ ei,
                                                int* __restrict__ cursor,
                                                int* __restrict__ csr_src,
                                                int* __restrict__ csr_eid,
                                                int E, int Etot)
{
    int i = blockIdx.x * 256 + threadIdx.x;
    if (i >= Etot) return;
    int src, dst;
    if (i < E) { src = ei[i]; dst = ei[E + i]; }
    else       { src = dst = i - E; }
    int pos = atomicAdd(&cursor[dst], 1);
    csr_src[pos] = src;
    csr_eid[pos] = i;
}

// ---------- fused per-dst attention: 2 nodes/block, 2 waves/node ----------
// Per wave: R5 geometry (head=lane>>4, sub=lane&15, 16B/lane), unroll-4, LDS
// logit buffer. Each wave scans HALF the node's edges; 2-way online-softmax
// state merge via LDS; finalize + epilogue split across the 2 waves.
// FINAL=false: write h (bf16). FINAL=true: fuse h@Wlin+blin -> relu -> sigmoid.
template <bool FINAL>
__global__ __launch_bounds__(256) void fused_attn(const ushort* __restrict__ xlxr,
                                                  const int* __restrict__ rowptr,
                                                  const int* __restrict__ csr_src,
                                                  const int* __restrict__ csr_eid,
                                                  const float* __restrict__ att,
                                                  float* __restrict__ alpha,
                                                  const float* __restrict__ bias,
                                                  const float* __restrict__ g,
                                                  const float* __restrict__ be,
                                                  const float* __restrict__ bmn,
                                                  const float* __restrict__ bvr,
                                                  ushort* __restrict__ hout,
                                                  const float* __restrict__ Wlin,
                                                  const float* __restrict__ blin,
                                                  float* __restrict__ out, int N)
{
    __shared__ __align__(16) float lraw[2][CAP][NH];   // 4 KB per-node logit buffer
    __shared__ float accs[2][2][8][64];                // 8 KB partial weighted sums
    __shared__ float smd[2][2][2][NH];                 // [nib][wv][m|den][head]
    const int tid = threadIdx.x;
    const int wid = tid >> 6;
    const int lane = tid & 63;
    const int nib = wid >> 1;          // node in block
    const int wv  = wid & 1;           // wave within node
    const int n = blockIdx.x * 2 + nib;
    const bool valid = n < N;
    const int head = lane >> 4, sub = lane & 15;
    const size_t foff = (size_t)head * HID + sub * 8;

    f32x2 xr2[4] = {}, at2[4] = {};
    if (valid) {
        ubf8p(xlxr + (size_t)n * F2 + FEAT + foff, xr2);
        const float4* a4 = (const float4*)(att + foff);
        float4 t0 = a4[0], t1 = a4[1];
        at2[0] = f32x2{t0.x, t0.y}; at2[1] = f32x2{t0.z, t0.w};
        at2[2] = f32x2{t1.x, t1.y}; at2[3] = f32x2{t1.z, t1.w};
    }

    int beg = 0, end = 0;
    if (valid) { beg = rowptr[n]; end = rowptr[n + 1]; }
    const int deg = end - beg;
    const bool big = deg > CAP;        // wave-uniform
    const int half = (deg + 1) >> 1;
    const int mybeg = beg + wv * half;
    const int myend = wv ? end : (beg + half);

    float mrun = -1e30f, den = 0.f;
    f32x2 acc2[4] = {};
    int k = mybeg;

    for (; k + 3 < myend; k += 4) {
        int s0 = csr_src[k],     s1 = csr_src[k + 1];
        int s2 = csr_src[k + 2], s3 = csr_src[k + 3];

        f32x2 xv0[4], xv1[4], xv2[4], xv3[4];
        ubf8p(xlxr + (size_t)s0 * F2 + foff, xv0);
        ubf8p(xlxr + (size_t)s1 * F2 + foff, xv1);
        ubf8p(xlxr + (size_t)s2 * F2 + foff, xv2);
        ubf8p(xlxr + (size_t)s3 * F2 + foff, xv3);

        f32x2 p0 = {}, p1 = {}, p2 = {}, p3 = {};
        #pragma unroll
        for (int j = 0; j < 4; ++j) {
            f32x2 t0 = xv0[j] + xr2[j];
            f32x2 t1 = xv1[j] + xr2[j];
            f32x2 t2 = xv2[j] + xr2[j];
            f32x2 t3 = xv3[j] + xr2[j];
            f32x2 u0 = t0 * NEG_SLOPE, u1 = t1 * NEG_SLOPE;
            f32x2 u2 = t2 * NEG_SLOPE, u3 = t3 * NEG_SLOPE;
            t0.x = fmaxf(t0.x, u0.x); t0.y = fmaxf(t0.y, u0.y);
            t1.x = fmaxf(t1.x, u1.x); t1.y = fmaxf(t1.y, u1.y);
            t2.x = fmaxf(t2.x, u2.x); t2.y = fmaxf(t2.y, u2.y);
            t3.x = fmaxf(t3.x, u3.x); t3.y = fmaxf(t3.y, u3.y);
            p0 += t0 * at2[j]; p1 += t1 * at2[j];
            p2 += t2 * at2[j]; p3 += t3 * at2[j];
        }
        float l0 = p0.x + p0.y, l1 = p1.x + p1.y;
        float l2 = p2.x + p2.y, l3 = p3.x + p3.y;
        #pragma unroll
        for (int off = 1; off < 16; off <<= 1) {
            l0 += __shfl_xor(l0, off, 64);
            l1 += __shfl_xor(l1, off, 64);
            l2 += __shfl_xor(l2, off, 64);
            l3 += __shfl_xor(l3, off, 64);
        }
        if (!big) {
            if (sub == 0) {
                int kk = k - beg;
                lraw[nib][kk + 0][head] = l0;
                lraw[nib][kk + 1][head] = l1;
                lraw[nib][kk + 2][head] = l2;
                lraw[nib][kk + 3][head] = l3;
            }
        } else if (sub == 0) {
            alpha[(size_t)csr_eid[k]     * NH + head] = l0;
            alpha[(size_t)csr_eid[k + 1] * NH + head] = l1;
            alpha[(size_t)csr_eid[k + 2] * NH + head] = l2;
            alpha[(size_t)csr_eid[k + 3] * NH + head] = l3;
        }
        float bmax = fmaxf(fmaxf(l0, l1), fmaxf(l2, l3));
        if (bmax > mrun) {
            float sc = __expf(mrun - bmax);
            den *= sc;
            #pragma unroll
            for (int j = 0; j < 4; ++j) acc2[j] *= sc;
            mrun = bmax;
        }
        float w0 = __expf(l0 - mrun), w1 = __expf(l1 - mrun);
        float w2 = __expf(l2 - mrun), w3 = __expf(l3 - mrun);
        den += (w0 + w1) + (w2 + w3);
        #pragma unroll
        for (int j = 0; j < 4; ++j)
            acc2[j] += (w0 * xv0[j] + w1 * xv1[j]) + (w2 * xv2[j] + w3 * xv3[j]);
    }

    for (; k < myend; ++k) {
        int src = csr_src[k];
        f32x2 xv[4];
        ubf8p(xlxr + (size_t)src * F2 + foff, xv);
        f32x2 ps = {};
        #pragma unroll
        for (int j = 0; j < 4; ++j) {
            f32x2 t = xv[j] + xr2[j];
            f32x2 u = t * NEG_SLOPE;
            t.x = fmaxf(t.x, u.x); t.y = fmaxf(t.y, u.y);
            ps += t * at2[j];
        }
        float s = ps.x + ps.y;
        #pragma unroll
        for (int off = 1; off < 16; off <<= 1) s += __shfl_xor(s, off, 64);
        if (!big) {
            if (sub == 0) lraw[nib][k - beg][head] = s;
        } else if (sub == 0) {
            alpha[(size_t)csr_eid[k] * NH + head] = s;
        }
        if (s > mrun) {
            float sc = __expf(mrun - s);
            den *= sc;
            #pragma unroll
            for (int j = 0; j < 4; ++j) acc2[j] *= sc;
            mrun = s;
        }
        float e = __expf(s - mrun);
        den += e;
        #pragma unroll
        for (int j = 0; j < 4; ++j) acc2[j] += e * xv[j];
    }

    // ---- stash partial state, merge across the node's 2 waves ----
    #pragma unroll
    for (int j = 0; j < 4; ++j) {
        accs[nib][wv][2 * j][lane]     = acc2[j].x;
        accs[nib][wv][2 * j + 1][lane] = acc2[j].y;
    }
    if (sub == 0) { smd[nib][wv][0][head] = mrun; smd[nib][wv][1][head] = den; }
    __syncthreads();

    // combined per-head (m, inv) for all 4 heads (static unroll -> registers)
    float mh[NH], ih[NH];
    #pragma unroll
    for (int h = 0; h < NH; ++h) {
        float a0 = smd[nib][0][0][h], a1 = smd[nib][1][0][h];
        float mg = fmaxf(a0, a1);
        float d = smd[nib][0][1][h] * __expf(a0 - mg) + smd[nib][1][1][h] * __expf(a1 - mg);
        mh[h] = mg; ih[h] = 1.f / (d + 1e-16f);
    }

    // ---- epilogue: head-mean + bias + BN + ReLU (wave 0 of each node) ----
    if (valid && wv == 0) {
        float m0 = smd[nib][0][0][head], m1 = smd[nib][1][0][head];
        float mg = fmaxf(m0, m1);
        float e0h = __expf(m0 - mg), e1h = __expf(m1 - mg);
        float dg = smd[nib][0][1][head] * e0h + smd[nib][1][1][head] * e1h;
        float invh = 1.f / (dg + 1e-16f);
        float t8[8];
        #pragma unroll
        for (int j = 0; j < 8; ++j) {
            float t = (accs[nib][0][j][lane] * e0h + accs[nib][1][j][lane] * e1h) * invh;
            t += __shfl_xor(t, 16, 64);
            t += __shfl_xor(t, 32, 64);
            t8[j] = t;
        }
        if (head == 0) {
            float o[8];
            #pragma unroll
            for (int j = 0; j < 8; ++j) {
                int c = sub * 8 + j;
                float s = t8[j] * 0.25f + bias[c];
                float bn = (s - bmn[c]) * rsqrtf(bvr[c] + BN_EPS) * g[c] + be[c];
                o[j] = fmaxf(bn, 0.f);
            }
            if (FINAL) {
                float p = 0.f;
                #pragma unroll
                for (int j = 0; j < 8; ++j) p += o[j] * Wlin[sub * 8 + j];
                p += __shfl_xor(p, 1, 64);
                p += __shfl_xor(p, 2, 64);
                p += __shfl_xor(p, 4, 64);
                p += __shfl_xor(p, 8, 64);
                if (sub == 0) {
                    float z = fmaxf(p + blin[0], 0.f);
                    out[n] = 1.f / (1.f + __expf(-z));
                }
            } else {
                uint4 ov;
                unsigned w[4];
                #pragma unroll
                for (int q = 0; q < 4; ++q)
                    w[q] = (unsigned)f2bf(o[2 * q]) | ((unsigned)f2bf(o[2 * q + 1]) << 16);
                ov.x = w[0]; ov.y = w[1]; ov.z = w[2]; ov.w = w[3];
                *(uint4*)(hout + (size_t)n * HID + sub * 8) = ov;
            }
        }
    }

    // ---- alpha finalize: each wave handles its own half ----
    if (valid && !big) {
        for (int e = (mybeg - beg) + lane; e < (myend - beg); e += 64) {
            int eid = csr_eid[beg + e];
            float4 r = *(const float4*)&lraw[nib][e][0];
            float4 o;
            o.x = __expf(r.x - mh[0]) * ih[0];
            o.y = __expf(r.y - mh[1]) * ih[1];
            o.z = __expf(r.z - mh[2]) * ih[2];
            o.w = __expf(r.w - mh[3]) * ih[3];
            *(float4*)&alpha[(size_t)eid * NH] = o;
        }
    } else if (valid) {
        // rare fallback: re-read own raw logits from global (same-wave writes)
        asm volatile("s_waitcnt vmcnt(0)" ::: "memory");
        float m0 = smd[nib][0][0][head], m1 = smd[nib][1][0][head];
        float mg = fmaxf(m0, m1);
        float dg = smd[nib][0][1][head] * __expf(m0 - mg) +
                   smd[nib][1][1][head] * __expf(m1 - mg);
        float invh = 1.f / (dg + 1e-16f);
        for (int k2 = mybeg + sub; k2 < myend; k2 += 16) {
            size_t idx = (size_t)csr_eid[k2] * NH + head;
            alpha[idx] = __expf(alpha[idx] - mg) * invh;
        }
    }
}

extern "C" void kernel_launch(void* const* d_in, const int* in_sizes, int n_in,
                              void* d_out, int out_size, void* d_ws, size_t ws_size,
                              hipStream_t stream)
{
    const float* x    = (const float*)d_in[0];
    const int*   ei   = (const int*)d_in[1];
    const float* Wl1  = (const float*)d_in[2];
    const float* Wr1  = (const float*)d_in[3];
    const float* att1 = (const float*)d_in[4];
    const float* b1   = (const float*)d_in[5];
    const float* Wl2  = (const float*)d_in[6];
    const float* Wr2  = (const float*)d_in[7];
    const float* att2 = (const float*)d_in[8];
    const float* b2   = (const float*)d_in[9];
    const float* g1   = (const float*)d_in[10];
    const float* be1  = (const float*)d_in[11];
    const float* m1   = (const float*)d_in[12];
    const float* v1   = (const float*)d_in[13];
    const float* g2   = (const float*)d_in[14];
    const float* be2  = (const float*)d_in[15];
    const float* m2   = (const float*)d_in[16];
    const float* v2   = (const float*)d_in[17];
    const float* Wlin = (const float*)d_in[18];
    const float* blin = (const float*)d_in[19];

    const int IN_C = 256;
    const int N = in_sizes[0] / IN_C;       // 10000
    const int E = in_sizes[1] / 2;          // 320000
    const int Etot = E + N;                 // with self loops

    float* out    = (float*)d_out;          // [N]
    float* alpha1 = out + N;                // [Etot*NH]
    float* alpha2 = alpha1 + (size_t)Etot * NH;

    // workspace layout (bytes)
    char* wsb = (char*)d_ws;
    ushort* xlxr  = (ushort*)wsb;                       wsb += (size_t)N * F2 * 2;
    ushort* hbbf  = (ushort*)wsb;                       wsb += (size_t)N * HID * 2;
    ushort* wt1   = (ushort*)wsb;                       wsb += (size_t)F2 * IN_C * 2;  // [1024][256]
    ushort* wt2   = (ushort*)wsb;                       wsb += (size_t)F2 * HID * 2;   // [1024][128]
    int*    deg    = (int*)wsb;                         wsb += (size_t)N * 4;
    int*    cursor = (int*)wsb;                         wsb += (size_t)N * 4;
    int*    rowptr = (int*)wsb;                         wsb += (size_t)(N + 1) * 4;
    int*    csrsrc = (int*)wsb;                         wsb += (size_t)Etot * 4;
    int*    csreid = (int*)wsb;

    dim3 blk(256);
    dim3 gemm_grid((N + 127) / 128, F2 / 128);
    int attn_blocks = (N + 1) / 2;
    int etot_blocks = (Etot + 255) / 256;

    // ---- weight transposes + CSR build ----
    hipMemsetAsync(deg, 0, (size_t)N * sizeof(int), stream);
    transpose_cast4<<<dim3(IN_C / 32, FEAT / 32, 4), blk, 0, stream>>>(
        Wl1, Wr1, Wl2, Wr2,
        wt1, wt1 + (size_t)FEAT * IN_C, wt2, wt2 + (size_t)FEAT * HID,
        IN_C, HID, FEAT);
    csr_count<<<etot_blocks, blk, 0, stream>>>(ei, deg, E, Etot);
    scan_rowptr<<<1, 1024, 0, stream>>>(deg, rowptr, cursor, N);
    csr_fill<<<etot_blocks, blk, 0, stream>>>(ei, cursor, csrsrc, csreid, E, Etot);

    // ================= layer 1 =================
    gemm_bf16<true><<<gemm_grid, blk, 0, stream>>>(x, wt1, xlxr, N, F2, IN_C);
    fused_attn<false><<<attn_blocks, blk, 0, stream>>>(xlxr, rowptr, csrsrc, csreid,
                                                       att1, alpha1, b1, g1, be1, m1, v1,
                                                       hbbf, Wlin, blin, out, N);

    // ================= layer 2 =================
    gemm_bf16<false><<<gemm_grid, blk, 0, stream>>>(hbbf, wt2, xlxr, N, F2, HID);
    fused_attn<true><<<attn_blocks, blk, 0, stream>>>(xlxr, rowptr, csrsrc, csreid,
                                                      att2, alpha2, b2, g2, be2, m2, v2,
                                                      hbbf, Wlin, blin, out, N);
}

// Round 14
// 195.922 us; speedup vs baseline: 1.1298x; 1.1298x over previous
//
#include <hip/hip_runtime.h>
#include <hip/hip_bf16.h>

#define HID 128
#define NH  4          // heads
#define FEAT (NH*HID)  // 512 per node per projection
#define F2   (2*FEAT)  // xl|xr packed row stride = 1024
#define NEG_SLOPE 0.2f
#define BN_EPS 1e-5f
#define CAP  128       // max buffered edges per node (deg ~ Poisson(32); fallback if exceeded)

typedef __attribute__((ext_vector_type(8))) short bf16x8;   // 8 bf16 = 4 VGPR
typedef __attribute__((ext_vector_type(4))) float f32x4;
typedef __attribute__((ext_vector_type(2))) float f32x2;

// ---------- helpers ----------
__device__ inline ushort f2bf(float f) {     // RNE f32 -> bf16
    unsigned u = __float_as_uint(f);
    return (ushort)((u + 0x7fffu + ((u >> 16) & 1u)) >> 16);
}
// unpack 8 bf16 into 4 float2 (channel pairs)
__device__ inline void ubf8p(const ushort* p, f32x2* o) {
    uint4 q = *(const uint4*)p;
    o[0] = f32x2{__uint_as_float(q.x << 16), __uint_as_float(q.x & 0xffff0000u)};
    o[1] = f32x2{__uint_as_float(q.y << 16), __uint_as_float(q.y & 0xffff0000u)};
    o[2] = f32x2{__uint_as_float(q.z << 16), __uint_as_float(q.z & 0xffff0000u)};
    o[3] = f32x2{__uint_as_float(q.w << 16), __uint_as_float(q.w & 0xffff0000u)};
}

// ---------- GEMM body: C[M][Nc] = A[M][K] @ Bt[Nc][K]^T, bf16 MFMA ----------
// 128x128 tile, BK=32, 256 threads = 4 waves (2x2), per wave 4x4 frags 16x16.
// CVT=true: A is f32, converted to bf16 during LDS staging.
template <bool CVT>
__device__ inline void gemm_body(const void* __restrict__ Av,
                                 const ushort* __restrict__ Bt,
                                 ushort* __restrict__ C,
                                 int M, int Nc, int K, int bm, int bn)
{
    __shared__ __align__(16) ushort As[128 * 40];  // row stride 40 (pad 8)
    __shared__ __align__(16) ushort Bs[128 * 40];
    const int tid = threadIdx.x;
    const int wid = tid >> 6, lane = tid & 63;
    const int wr = wid >> 1, wc = wid & 1;
    const int l15 = lane & 15, l4 = lane >> 4;

    f32x4 acc[4][4] = {};

    for (int k0 = 0; k0 < K; k0 += 32) {
        #pragma unroll
        for (int s = 0; s < 2; ++s) {               // A,B: 512 chunks of 8 elems each
            int c = tid + s * 256;
            int r = c >> 2, cc = (c & 3) * 8;
            int gr = bm + r;
            if (CVT) {
                const float* A = (const float*)Av;
                float4 lo = make_float4(0.f, 0.f, 0.f, 0.f);
                float4 hi = make_float4(0.f, 0.f, 0.f, 0.f);
                if (gr < M) {
                    lo = *(const float4*)(A + (size_t)gr * K + k0 + cc);
                    hi = *(const float4*)(A + (size_t)gr * K + k0 + cc + 4);
                }
                ushort4 p0 = make_ushort4(f2bf(lo.x), f2bf(lo.y), f2bf(lo.z), f2bf(lo.w));
                ushort4 p1 = make_ushort4(f2bf(hi.x), f2bf(hi.y), f2bf(hi.z), f2bf(hi.w));
                *(ushort4*)&As[r * 40 + cc] = p0;
                *(ushort4*)&As[r * 40 + cc + 4] = p1;
            } else {
                const ushort* A = (const ushort*)Av;
                uint4 v = make_uint4(0, 0, 0, 0);
                if (gr < M) v = *(const uint4*)(A + (size_t)gr * K + k0 + cc);
                *(uint4*)&As[r * 40 + cc] = v;
            }
            uint4 w = *(const uint4*)(Bt + (size_t)(bn + r) * K + k0 + cc);
            *(uint4*)&Bs[r * 40 + cc] = w;
        }
        __syncthreads();
        bf16x8 bfr[4];
        #pragma unroll
        for (int n = 0; n < 4; ++n)
            bfr[n] = *(const bf16x8*)&Bs[(wc * 64 + n * 16 + l15) * 40 + l4 * 8];
        #pragma unroll
        for (int m = 0; m < 4; ++m) {
            bf16x8 afr = *(const bf16x8*)&As[(wr * 64 + m * 16 + l15) * 40 + l4 * 8];
            #pragma unroll
            for (int n = 0; n < 4; ++n)
                acc[m][n] = __builtin_amdgcn_mfma_f32_16x16x32_bf16(afr, bfr[n], acc[m][n], 0, 0, 0);
        }
        __syncthreads();
    }
    #pragma unroll
    for (int m = 0; m < 4; ++m)
        #pragma unroll
        for (int n = 0; n < 4; ++n)
            #pragma unroll
            for (int r = 0; r < 4; ++r) {
                int row = bm + wr * 64 + m * 16 + l4 * 4 + r;
                int col = bn + wc * 64 + n * 16 + l15;
                if (row < M) C[(size_t)row * Nc + col] = f2bf(acc[m][n][r]);
            }
}

// ---------- standalone GEMM (layer 2) ----------
__global__ __launch_bounds__(256) void gemm_bf16(const ushort* __restrict__ A,
                                                 const ushort* __restrict__ Bt,
                                                 ushort* __restrict__ C,
                                                 int M, int Nc, int K)
{
    gemm_body<false>(A, Bt, C, M, Nc, K, blockIdx.x * 128, blockIdx.y * 128);
}

// ---------- transpose body: in[K][Nc] f32 -> out[Nc][K] bf16, one 32x32 tile ----------
__device__ inline void transpose_body(const float* __restrict__ in,
                                      ushort* __restrict__ out,
                                      int K, int Nc, int bk, int bc)
{
    __shared__ float t[32][33];
    int r = threadIdx.x >> 3, c4 = (threadIdx.x & 7) * 4;
    float4 v = *(const float4*)(in + (size_t)(bk + r) * Nc + bc + c4);
    t[r][c4 + 0] = v.x; t[r][c4 + 1] = v.y; t[r][c4 + 2] = v.z; t[r][c4 + 3] = v.w;
    __syncthreads();
    ushort4 o;
    o.x = f2bf(t[c4 + 0][r]); o.y = f2bf(t[c4 + 1][r]);
    o.z = f2bf(t[c4 + 2][r]); o.w = f2bf(t[c4 + 3][r]);
    *(ushort4*)(out + (size_t)(bc + r) * K + bk + c4) = o;
}

// ---------- prep A: weight transposes (blocks 0..383) + csr_count (rest) ----------
// z<2: K=IN_C (8x16 blocks each); z>=2: K=HID (4x16 blocks each).
__global__ __launch_bounds__(256) void prep_a(const float* __restrict__ Wl1,
                                              const float* __restrict__ Wr1,
                                              const float* __restrict__ Wl2,
                                              const float* __restrict__ Wr2,
                                              ushort* __restrict__ o0,
                                              ushort* __restrict__ o1,
                                              ushort* __restrict__ o2,
                                              ushort* __restrict__ o3,
                                              int IN_C,
                                              const int* __restrict__ ei,
                                              int* __restrict__ deg,
                                              int E, int Etot)
{
    const int b = blockIdx.x;
    if (b < 384) {
        int z, idx;
        if (b < 256) { z = b >> 7; idx = b & 127; }
        else         { z = 2 + ((b - 256) >> 6); idx = (b - 256) & 63; }
        const float* in  = (z == 0) ? Wl1 : (z == 1) ? Wr1 : (z == 2) ? Wl2 : Wr2;
        ushort*      out = (z == 0) ? o0  : (z == 1) ? o1  : (z == 2) ? o2  : o3;
        const int K = (z < 2) ? IN_C : HID;
        int bx = (z < 2) ? (idx & 7) : (idx & 3);
        int by = (z < 2) ? (idx >> 3) : (idx >> 2);
        transpose_body(in, out, K, FEAT, bx * 32, by * 32);
    } else {
        int i = (b - 384) * 256 + threadIdx.x;
        if (i >= Etot) return;
        int dst = (i < E) ? ei[E + i] : (i - E);
        atomicAdd(&deg[dst], 1);
    }
}

// ---------- prep B: GEMM1 (CVT, blocks 0..GB-1) + csr_fill (rest) ----------
__global__ __launch_bounds__(256) void prep_b(const float* __restrict__ x,
                                              const ushort* __restrict__ wt1,
                                              ushort* __restrict__ xlxr,
                                              int M, int Nc, int K, int nbx, int GB,
                                              const int* __restrict__ ei,
                                              int* __restrict__ cursor,
                                              int* __restrict__ csr_src,
                                              int* __restrict__ csr_eid,
                                              int E, int Etot)
{
    const int b = blockIdx.x;
    if (b < GB) {
        gemm_body<true>(x, wt1, xlxr, M, Nc, K, (b % nbx) * 128, (b / nbx) * 128);
    } else {
        int i = (b - GB) * 256 + threadIdx.x;
        if (i >= Etot) return;
        int src, dst;
        if (i < E) { src = ei[i]; dst = ei[E + i]; }
        else       { src = dst = i - E; }
        int pos = atomicAdd(&cursor[dst], 1);
        csr_src[pos] = src;
        csr_eid[pos] = i;
    }
}

// ---------- single-block exclusive scan of deg -> rowptr, cursor ----------
__global__ __launch_bounds__(1024) void scan_rowptr(const int* __restrict__ deg,
                                                    int* __restrict__ rowptr,
                                                    int* __restrict__ cursor,
                                                    int N)
{
    __shared__ int part[1024];
    int t = threadIdx.x;
    int chunk = (N + 1023) / 1024;
    int lo = t * chunk;
    int hi = lo + chunk; if (hi > N) hi = N; if (lo > N) lo = N;
    int s = 0;
    for (int i = lo; i < hi; ++i) s += deg[i];
    part[t] = s;
    __syncthreads();
    for (int off = 1; off < 1024; off <<= 1) {
        int v = (t >= off) ? part[t - off] : 0;
        __syncthreads();
        part[t] += v;
        __syncthreads();
    }
    int base = (t == 0) ? 0 : part[t - 1];
    for (int i = lo; i < hi; ++i) {
        rowptr[i] = base;
        cursor[i] = base;
        base += deg[i];
    }
    if (t == 1023) rowptr[N] = part[1023];
}

// ---------- fused per-dst attention (R12: unroll-4, LDS logit buffer, pk-f32) ----------
// One wave per node; head = lane>>4, sub = lane&15 covers 8 channels (16B/lane).
// FINAL=false: write h (bf16). FINAL=true: fuse h@Wlin+blin -> relu -> sigmoid.
template <bool FINAL>
__global__ __launch_bounds__(256) void fused_attn(const ushort* __restrict__ xlxr,
                                                  const int* __restrict__ rowptr,
                                                  const int* __restrict__ csr_src,
                                                  const int* __restrict__ csr_eid,
                                                  const float* __restrict__ att,
                                                  float* __restrict__ alpha,
                                                  const float* __restrict__ bias,
                                                  const float* __restrict__ g,
                                                  const float* __restrict__ be,
                                                  const float* __restrict__ bmn,
                                                  const float* __restrict__ bvr,
                                                  ushort* __restrict__ hout,
                                                  const float* __restrict__ Wlin,
                                                  const float* __restrict__ blin,
                                                  float* __restrict__ out, int N)
{
    __shared__ __align__(16) float lraw[4][CAP][NH];   // 8 KB, wave-local
    int n = (blockIdx.x * 256 + threadIdx.x) >> 6;
    int lane = threadIdx.x & 63;
    if (n >= N) return;
    const int wid = (threadIdx.x >> 6);
    int head = lane >> 4, sub = lane & 15;
    const size_t foff = (size_t)head * HID + sub * 8;

    f32x2 xr2[4], at2[4];
    ubf8p(xlxr + (size_t)n * F2 + FEAT + foff, xr2);
    {
        const float4* a4 = (const float4*)(att + foff);
        float4 t0 = a4[0], t1 = a4[1];
        at2[0] = f32x2{t0.x, t0.y}; at2[1] = f32x2{t0.z, t0.w};
        at2[2] = f32x2{t1.x, t1.y}; at2[3] = f32x2{t1.z, t1.w};
    }

    float mrun = -1e30f, den = 0.f;
    f32x2 acc2[4] = {};
    const int beg = rowptr[n], end = rowptr[n + 1];
    const int deg = end - beg;
    const bool big = deg > CAP;       // wave-uniform
    int k = beg;

    for (; k + 3 < end; k += 4) {
        int s0 = csr_src[k],     s1 = csr_src[k + 1];
        int s2 = csr_src[k + 2], s3 = csr_src[k + 3];

        f32x2 xv0[4], xv1[4], xv2[4], xv3[4];
        ubf8p(xlxr + (size_t)s0 * F2 + foff, xv0);
        ubf8p(xlxr + (size_t)s1 * F2 + foff, xv1);
        ubf8p(xlxr + (size_t)s2 * F2 + foff, xv2);
        ubf8p(xlxr + (size_t)s3 * F2 + foff, xv3);

        f32x2 p0 = {}, p1 = {}, p2 = {}, p3 = {};
        #pragma unroll
        for (int j = 0; j < 4; ++j) {
            f32x2 t0 = xv0[j] + xr2[j];
            f32x2 t1 = xv1[j] + xr2[j];
            f32x2 t2 = xv2[j] + xr2[j];
            f32x2 t3 = xv3[j] + xr2[j];
            f32x2 u0 = t0 * NEG_SLOPE, u1 = t1 * NEG_SLOPE;
            f32x2 u2 = t2 * NEG_SLOPE, u3 = t3 * NEG_SLOPE;
            t0.x = fmaxf(t0.x, u0.x); t0.y = fmaxf(t0.y, u0.y);
            t1.x = fmaxf(t1.x, u1.x); t1.y = fmaxf(t1.y, u1.y);
            t2.x = fmaxf(t2.x, u2.x); t2.y = fmaxf(t2.y, u2.y);
            t3.x = fmaxf(t3.x, u3.x); t3.y = fmaxf(t3.y, u3.y);
            p0 += t0 * at2[j]; p1 += t1 * at2[j];
            p2 += t2 * at2[j]; p3 += t3 * at2[j];
        }
        float l0 = p0.x + p0.y, l1 = p1.x + p1.y;
        float l2 = p2.x + p2.y, l3 = p3.x + p3.y;
        #pragma unroll
        for (int off = 1; off < 16; off <<= 1) {
            l0 += __shfl_xor(l0, off, 64);
            l1 += __shfl_xor(l1, off, 64);
            l2 += __shfl_xor(l2, off, 64);
            l3 += __shfl_xor(l3, off, 64);
        }
        if (!big) {
            if (sub == 0) {
                int kk = k - beg;
                lraw[wid][kk + 0][head] = l0;
                lraw[wid][kk + 1][head] = l1;
                lraw[wid][kk + 2][head] = l2;
                lraw[wid][kk + 3][head] = l3;
            }
        } else if (sub == 0) {
            alpha[(size_t)csr_eid[k]     * NH + head] = l0;
            alpha[(size_t)csr_eid[k + 1] * NH + head] = l1;
            alpha[(size_t)csr_eid[k + 2] * NH + head] = l2;
            alpha[(size_t)csr_eid[k + 3] * NH + head] = l3;
        }
        float bmax = fmaxf(fmaxf(l0, l1), fmaxf(l2, l3));
        if (bmax > mrun) {
            float sc = __expf(mrun - bmax);
            den *= sc;
            #pragma unroll
            for (int j = 0; j < 4; ++j) acc2[j] *= sc;
            mrun = bmax;
        }
        float w0 = __expf(l0 - mrun), w1 = __expf(l1 - mrun);
        float w2 = __expf(l2 - mrun), w3 = __expf(l3 - mrun);
        den += (w0 + w1) + (w2 + w3);
        #pragma unroll
        for (int j = 0; j < 4; ++j)
            acc2[j] += (w0 * xv0[j] + w1 * xv1[j]) + (w2 * xv2[j] + w3 * xv3[j]);
    }

    for (; k < end; ++k) {
        int src = csr_src[k];
        f32x2 xv[4];
        ubf8p(xlxr + (size_t)src * F2 + foff, xv);
        f32x2 ps = {};
        #pragma unroll
        for (int j = 0; j < 4; ++j) {
            f32x2 t = xv[j] + xr2[j];
            f32x2 u = t * NEG_SLOPE;
            t.x = fmaxf(t.x, u.x); t.y = fmaxf(t.y, u.y);
            ps += t * at2[j];
        }
        float s = ps.x + ps.y;
        #pragma unroll
        for (int off = 1; off < 16; off <<= 1) s += __shfl_xor(s, off, 64);
        if (!big) {
            if (sub == 0) lraw[wid][k - beg][head] = s;
        } else if (sub == 0) {
            alpha[(size_t)csr_eid[k] * NH + head] = s;
        }
        if (s > mrun) {
            float sc = __expf(mrun - s);
            den *= sc;
            #pragma unroll
            for (int j = 0; j < 4; ++j) acc2[j] *= sc;
            mrun = s;
        }
        float e = __expf(s - mrun);
        den += e;
        #pragma unroll
        for (int j = 0; j < 4; ++j) acc2[j] += e * xv[j];
    }

    float inv = 1.f / (den + 1e-16f);

    // head-mean via cross-head shuffles
    float t8[8];
    #pragma unroll
    for (int j = 0; j < 4; ++j) {
        float ta = acc2[j].x * inv;
        float tb = acc2[j].y * inv;
        ta += __shfl_xor(ta, 16, 64);
        ta += __shfl_xor(ta, 32, 64);
        tb += __shfl_xor(tb, 16, 64);
        tb += __shfl_xor(tb, 32, 64);
        t8[2 * j] = ta; t8[2 * j + 1] = tb;
    }
    if (head == 0) {
        float o[8];
        #pragma unroll
        for (int j = 0; j < 8; ++j) {
            int c = sub * 8 + j;
            float s = t8[j] * 0.25f + bias[c];
            float bn = (s - bmn[c]) * rsqrtf(bvr[c] + BN_EPS) * g[c] + be[c];
            o[j] = fmaxf(bn, 0.f);
        }
        if (FINAL) {
            float p = 0.f;
            #pragma unroll
            for (int j = 0; j < 8; ++j) p += o[j] * Wlin[sub * 8 + j];
            p += __shfl_xor(p, 1, 64);
            p += __shfl_xor(p, 2, 64);
            p += __shfl_xor(p, 4, 64);
            p += __shfl_xor(p, 8, 64);
            if (sub == 0) {
                float z = fmaxf(p + blin[0], 0.f);
                out[n] = 1.f / (1.f + __expf(-z));
            }
        } else {
            uint4 ov;
            unsigned w[4];
            #pragma unroll
            for (int q = 0; q < 4; ++q)
                w[q] = (unsigned)f2bf(o[2 * q]) | ((unsigned)f2bf(o[2 * q + 1]) << 16);
            ov.x = w[0]; ov.y = w[1]; ov.z = w[2]; ov.w = w[3];
            *(uint4*)(hout + (size_t)n * HID + sub * 8) = ov;
        }
    }

    // ---- alpha finalize ----
    float m_h[NH], i_h[NH];
    #pragma unroll
    for (int h = 0; h < NH; ++h) {
        m_h[h] = __shfl(mrun, h * 16, 64);
        float d = __shfl(den, h * 16, 64);
        i_h[h] = 1.f / (d + 1e-16f);
    }
    if (!big) {
        // each lane finalizes all 4 heads of one edge from LDS, single 16B write
        for (int e = lane; e < deg; e += 64) {
            int eid = csr_eid[beg + e];
            float4 r = *(const float4*)&lraw[wid][e][0];
            float4 o;
            o.x = __expf(r.x - m_h[0]) * i_h[0];
            o.y = __expf(r.y - m_h[1]) * i_h[1];
            o.z = __expf(r.z - m_h[2]) * i_h[2];
            o.w = __expf(r.w - m_h[3]) * i_h[3];
            *(float4*)&alpha[(size_t)eid * NH] = o;
        }
    } else {
        // rare fallback: re-read own raw logits from global
        asm volatile("s_waitcnt vmcnt(0)" ::: "memory");
        float minv = i_h[head];
        for (int k2 = beg + sub; k2 < end; k2 += 16) {
            size_t idx = (size_t)csr_eid[k2] * NH + head;
            alpha[idx] = __expf(alpha[idx] - m_h[head]) * minv;
        }
    }
}

extern "C" void kernel_launch(void* const* d_in, const int* in_sizes, int n_in,
                              void* d_out, int out_size, void* d_ws, size_t ws_size,
                              hipStream_t stream)
{
    const float* x    = (const float*)d_in[0];
    const int*   ei   = (const int*)d_in[1];
    const float* Wl1  = (const float*)d_in[2];
    const float* Wr1  = (const float*)d_in[3];
    const float* att1 = (const float*)d_in[4];
    const float* b1   = (const float*)d_in[5];
    const float* Wl2  = (const float*)d_in[6];
    const float* Wr2  = (const float*)d_in[7];
    const float* att2 = (const float*)d_in[8];
    const float* b2   = (const float*)d_in[9];
    const float* g1   = (const float*)d_in[10];
    const float* be1  = (const float*)d_in[11];
    const float* m1   = (const float*)d_in[12];
    const float* v1   = (const float*)d_in[13];
    const float* g2   = (const float*)d_in[14];
    const float* be2  = (const float*)d_in[15];
    const float* m2   = (const float*)d_in[16];
    const float* v2   = (const float*)d_in[17];
    const float* Wlin = (const float*)d_in[18];
    const float* blin = (const float*)d_in[19];

    const int IN_C = 256;
    const int N = in_sizes[0] / IN_C;       // 10000
    const int E = in_sizes[1] / 2;          // 320000
    const int Etot = E + N;                 // with self loops

    float* out    = (float*)d_out;          // [N]
    float* alpha1 = out + N;                // [Etot*NH]
    float* alpha2 = alpha1 + (size_t)Etot * NH;

    // workspace layout (bytes)
    char* wsb = (char*)d_ws;
    ushort* xlxr  = (ushort*)wsb;                       wsb += (size_t)N * F2 * 2;
    ushort* hbbf  = (ushort*)wsb;                       wsb += (size_t)N * HID * 2;
    ushort* wt1   = (ushort*)wsb;                       wsb += (size_t)F2 * IN_C * 2;  // [1024][256]
    ushort* wt2   = (ushort*)wsb;                       wsb += (size_t)F2 * HID * 2;   // [1024][128]
    int*    deg    = (int*)wsb;                         wsb += (size_t)N * 4;
    int*    cursor = (int*)wsb;                         wsb += (size_t)N * 4;
    int*    rowptr = (int*)wsb;                         wsb += (size_t)(N + 1) * 4;
    int*    csrsrc = (int*)wsb;                         wsb += (size_t)Etot * 4;
    int*    csreid = (int*)wsb;

    dim3 blk(256);
    const int nbx = (N + 127) / 128;                    // 79
    const int GB  = nbx * (F2 / 128);                   // 632 gemm blocks
    const int etot_blocks = (Etot + 255) / 256;         // 1290
    int node_wave_blocks = (N + 3) / 4;

    // ---- stage 0: zero deg ----
    hipMemsetAsync(deg, 0, (size_t)N * sizeof(int), stream);

    // ---- stage 1: weight transposes || csr_count ----
    prep_a<<<384 + etot_blocks, blk, 0, stream>>>(
        Wl1, Wr1, Wl2, Wr2,
        wt1, wt1 + (size_t)FEAT * IN_C, wt2, wt2 + (size_t)FEAT * HID,
        IN_C, ei, deg, E, Etot);

    // ---- stage 2: scan ----
    scan_rowptr<<<1, 1024, 0, stream>>>(deg, rowptr, cursor, N);

    // ---- stage 3: GEMM1 (f32->bf16 fused) || csr_fill ----
    prep_b<<<GB + etot_blocks, blk, 0, stream>>>(
        x, wt1, xlxr, N, F2, IN_C, nbx, GB,
        ei, cursor, csrsrc, csreid, E, Etot);

    // ---- layer 1 attention ----
    fused_attn<false><<<node_wave_blocks, blk, 0, stream>>>(xlxr, rowptr, csrsrc, csreid,
                                                            att1, alpha1, b1, g1, be1, m1, v1,
                                                            hbbf, Wlin, blin, out, N);

    // ---- layer 2 ----
    gemm_bf16<<<dim3(nbx, F2 / 128), blk, 0, stream>>>(hbbf, wt2, xlxr, N, F2, HID);
    fused_attn<true><<<node_wave_blocks, blk, 0, stream>>>(xlxr, rowptr, csrsrc, csreid,
                                                           att2, alpha2, b2, g2, be2, m2, v2,
                                                           hbbf, Wlin, blin, out, N);
}